// Round 9
// baseline (108.162 us; speedup 1.0000x reference)
//
#include <hip/hip_runtime.h>
#include <math.h>

#define KS    31
#define KSP   32           // padded taps per row (col 31: env=0)
#define PADV  15
#define IMG   320
#define NOUT  289          // valid centered outputs (i in [15, 304))
#define TB    8            // 8x8 output pixels per block
#define TROWS 38           // TB + KS - 1
#define TSTR  39           // padded LDS row stride
#define NTH   180
#define TABQ  (KSP * KSP)  // 1024 float2 per theta (row 31: zeros)
#define RBLK  128          // reduction blocks
#define NTHR  512          // 64 pixels x 8 parts

// ---- per-theta (env, phi) table: w(t,f,tap) = env * cos_rev(f0 * phi) ----
__global__ __launch_bounds__(256) void build_eftab(float2* __restrict__ tab) {
    const int t = blockIdx.x;
    const float th = ((float)t / 180.0f) * 3.14159265358979323846f;
    float st, ct;
    sincosf(th, &st, &ct);
    float2* base = tab + (size_t)t * TABQ;
    for (int e = threadIdx.x; e < TABQ; e += 256) {
        int dy = e >> 5, dx = e & 31;
        float2 v = make_float2(0.0f, 0.0f);
        if (dy < KS && dx < KS) {
            float y = (float)(dy - PADV);
            float x = (float)(dx - PADV);
            float x_t = fmaf(x,  ct, y * st);
            float y_t = fmaf(-x, st, y * ct);
            float gamma = fmaf(0.04f, fabsf(y_t), 1.0f);      // 1 + 0.6|y_t|/15
            float gyt = gamma * y_t;
            float env = expf(-fmaf(x_t, x_t, gyt * gyt) * (1.0f / 72.0f));
            float phi = fmaf(x_t * y_t, (1.0f / 45.0f), x_t); // f_local*x_t = f0*phi
            v = make_float2(env, phi);
        }
        base[e] = v;
    }
}

// 512 threads = 64 pixels x 8 row-parts. Part q handles rows q*4..q*4+3
// (row 31 / col 31 have env==0; only the LDS row address needs clamping).
__global__ __launch_bounds__(NTHR) void gabor_conv(
    const float* __restrict__ fp, const int* __restrict__ fmap,
    const int* __restrict__ tmap, const float2* __restrict__ tab,
    float* __restrict__ out)
{
    __shared__ float tile[TROWS * TSTR];
    const int bh = blockIdx.y * TB;
    const int bw = blockIdx.x * TB;
    const int tid = threadIdx.x;

    for (int i = tid; i < TROWS * TSTR; i += NTHR) {
        int r = i / TSTR, c = i - r * TSTR;
        int gr = bh + r, gc = bw + c;
        tile[i] = (gr < IMG && gc < IMG) ? fp[gr * IMG + gc] : 0.0f;
    }
    __syncthreads();

    const int pixel = tid >> 3, part = tid & 7;   // parts adjacent lanes
    const int px = pixel & 7, py = pixel >> 3;
    const int oy = bh + py, ox = bw + px;
    const bool valid = (oy < NOUT) && (ox < NOUT);

    float acc0 = 0.0f, acc1 = 0.0f;
    if (valid) {
        const int iy = oy + PADV, ix = ox + PADV;
        const int theta = tmap[iy * IMG + ix];
        const float f0 = 0.025f + 0.0015f * (float)fmap[iy * IMG + ix];
        const int r0 = part * 4;
        const float2* __restrict__ efb = tab + (size_t)theta * TABQ + (size_t)r0 * KSP;

        #pragma unroll
        for (int r = 0; r < 4; ++r) {
            const int dy  = r0 + r;
            const int dya = (dy > 30) ? 30 : dy;       // LDS row clamp (dy==31 only)
            const float* trow = &tile[(py + dya) * TSTR + px];

            // batch the whole padded table row (256 B) into registers
            const float4* ef4 = (const float4*)(efb + (size_t)r * KSP);
            float4 tw[16];
            #pragma unroll
            for (int i = 0; i < 16; ++i) tw[i] = ef4[i];
            #pragma unroll
            for (int i = 0; i < 16; ++i)
                asm volatile("" : "+v"(tw[i].x), "+v"(tw[i].y),
                                  "+v"(tw[i].z), "+v"(tw[i].w));

            #pragma unroll
            for (int c = 0; c < KSP; ++c) {
                float env = (c & 1) ? tw[c >> 1].z : tw[c >> 1].x;
                float phi = (c & 1) ? tw[c >> 1].w : tw[c >> 1].y;
                float cc  = __builtin_amdgcn_cosf(f0 * phi);  // cos(2*pi*f_local*x_t)
                float w   = env * cc;                          // env==0 pads c=31, dy=31
                if (c & 1) acc1 = fmaf(trow[c], w, acc1);
                else       acc0 = fmaf(trow[c], w, acc0);
            }
        }
    }

    // combine the 8 row-parts (adjacent lanes) of each pixel
    float v = acc0 + acc1;
    v += __shfl_xor(v, 1, 64);
    v += __shfl_xor(v, 2, 64);
    v += __shfl_xor(v, 4, 64);

    if (valid && part == 0)
        out[(oy + PADV) * IMG + (ox + PADV)] = v;
}

__global__ __launch_bounds__(256) void border_copy(
    const float* __restrict__ fp, float* __restrict__ out)
{
    int p = blockIdx.x * 256 + threadIdx.x;
    if (p >= IMG * IMG) return;
    int i = p / IMG, j = p - i * IMG;
    bool inner = (i >= PADV) && (i < PADV + NOUT) && (j >= PADV) && (j < PADV + NOUT);
    if (!inner) out[p] = fp[p];
}

// ---- stage 1: grid-stride min/max over out -> per-block partials ----
__global__ __launch_bounds__(256) void reduce_partials(
    const float* __restrict__ out, float2* __restrict__ part)
{
    __shared__ float smin[4], smax[4];
    float vmin = INFINITY, vmax = -INFINITY;
    for (int p = blockIdx.x * 256 + threadIdx.x; p < IMG * IMG; p += RBLK * 256) {
        float v = out[p];
        vmin = fminf(vmin, v);
        vmax = fmaxf(vmax, v);
    }
    for (int off = 32; off; off >>= 1) {
        vmin = fminf(vmin, __shfl_down(vmin, off, 64));
        vmax = fmaxf(vmax, __shfl_down(vmax, off, 64));
    }
    const int wave = threadIdx.x >> 6;
    if ((threadIdx.x & 63) == 0) { smin[wave] = vmin; smax[wave] = vmax; }
    __syncthreads();
    if (threadIdx.x == 0) {
        vmin = fminf(fminf(smin[0], smin[1]), fminf(smin[2], smin[3]));
        vmax = fmaxf(fmaxf(smax[0], smax[1]), fmaxf(smax[2], smax[3]));
        part[blockIdx.x] = make_float2(vmin, vmax);
    }
}

// ---- stage 2: single block reduces RBLK partials -> mm (plain floats) ----
__global__ __launch_bounds__(RBLK) void reduce_final(
    const float2* __restrict__ part, float* __restrict__ mm)
{
    __shared__ float smin[2], smax[2];
    float2 v = part[threadIdx.x];
    float vmin = v.x, vmax = v.y;
    for (int off = 32; off; off >>= 1) {
        vmin = fminf(vmin, __shfl_down(vmin, off, 64));
        vmax = fmaxf(vmax, __shfl_down(vmax, off, 64));
    }
    const int wave = threadIdx.x >> 6;
    if ((threadIdx.x & 63) == 0) { smin[wave] = vmin; smax[wave] = vmax; }
    __syncthreads();
    if (threadIdx.x == 0) {
        mm[0] = fminf(smin[0], smin[1]);
        mm[1] = fmaxf(smax[0], smax[1]);
    }
}

__global__ __launch_bounds__(256) void finalize(
    float* __restrict__ out, const float* __restrict__ mm)
{
    int p = blockIdx.x * 256 + threadIdx.x;
    if (p >= IMG * IMG) return;
    float mn = mm[0];
    float mx = mm[1] - mn;               // max(out - min) == max0 - min0
    float v  = out[p] - mn;
    if (mx != 0.0f) v = v / mx * 100.0f;
    out[p] = (v > 55.0f) ? 100.0f : 0.0f;
}

extern "C" void kernel_launch(void* const* d_in, const int* in_sizes, int n_in,
                              void* d_out, int out_size, void* d_ws, size_t ws_size,
                              hipStream_t stream) {
    const float* fp   = (const float*)d_in[0];
    const int*   fmap = (const int*)d_in[1];
    const int*   tmap = (const int*)d_in[2];
    float* out = (float*)d_out;

    float*  mm   = (float*)d_ws;                          // 2 floats
    float2* part = (float2*)((char*)d_ws + 256);          // RBLK float2
    float2* tab  = (float2*)((char*)d_ws + 4096);         // 180*1024*8 = 1.47 MB

    hipLaunchKernelGGL(build_eftab, dim3(NTH), dim3(256), 0, stream, tab);

    dim3 g((NOUT + TB - 1) / TB, (NOUT + TB - 1) / TB);   // 37 x 37
    hipLaunchKernelGGL(gabor_conv, g, dim3(NTHR), 0, stream, fp, fmap, tmap, tab, out);

    int nblk = (IMG * IMG + 255) / 256;
    hipLaunchKernelGGL(border_copy,     dim3(nblk), dim3(256), 0, stream, fp, out);
    hipLaunchKernelGGL(reduce_partials, dim3(RBLK), dim3(256), 0, stream, out, part);
    hipLaunchKernelGGL(reduce_final,    dim3(1),    dim3(RBLK), 0, stream, part, mm);
    hipLaunchKernelGGL(finalize,        dim3(nblk), dim3(256), 0, stream, out, mm);
}

// Round 10
// 50.652 us; speedup vs baseline: 2.1354x; 2.1354x over previous
//
#include <hip/hip_runtime.h>
#include <math.h>

#define KS    31
#define KSP   32           // padded taps per row (col/row 31: env=0)
#define PADV  15
#define IMG   320
#define NOUT  289          // valid centered outputs (i in [15, 304))
#define NTH   180
#define TABQ  (KSP * KSP)  // 1024 float2 per theta
#define RBLK  128          // reduction blocks

// conv block geometry: 8 pixels (4 wide x 2 high), one pixel per 32-lane half
#define PBX   4
#define PBY   2
#define TROWS (PBY + KSP - 1)   // 33
#define TCOLS (PBX + KSP - 1)   // 35
#define TSTR  37                // odd stride

// ---- per-theta (env, phi) table: w(t,f,tap) = env * cos_rev(f0 * phi) ----
__global__ __launch_bounds__(256) void build_eftab(float2* __restrict__ tab) {
    const int t = blockIdx.x;
    const float th = ((float)t / 180.0f) * 3.14159265358979323846f;
    float st, ct;
    sincosf(th, &st, &ct);
    float2* base = tab + (size_t)t * TABQ;
    for (int e = threadIdx.x; e < TABQ; e += 256) {
        int dy = e >> 5, dx = e & 31;
        float2 v = make_float2(0.0f, 0.0f);
        if (dy < KS && dx < KS) {
            float y = (float)(dy - PADV);
            float x = (float)(dx - PADV);
            float x_t = fmaf(x,  ct, y * st);
            float y_t = fmaf(-x, st, y * ct);
            float gamma = fmaf(0.04f, fabsf(y_t), 1.0f);      // 1 + 0.6|y_t|/15
            float gyt = gamma * y_t;
            float env = expf(-fmaf(x_t, x_t, gyt * gyt) * (1.0f / 72.0f));
            float phi = fmaf(x_t * y_t, (1.0f / 45.0f), x_t); // f_local*x_t = f0*phi
            v = make_float2(env, phi);
        }
        base[e] = v;
    }
}

// 256 threads = 4 waves = 8 pixels; each 32-lane half owns one pixel and
// streams its 8 KB (env,phi) slab with contiguous float4 loads.
__global__ __launch_bounds__(256) void gabor_conv(
    const float* __restrict__ fp, const int* __restrict__ fmap,
    const int* __restrict__ tmap, const float2* __restrict__ tab,
    float* __restrict__ out)
{
    __shared__ float tile[TROWS * TSTR];
    const int bh = blockIdx.y * PBY;
    const int bw = blockIdx.x * PBX;
    const int tid = threadIdx.x;

    for (int i = tid; i < TROWS * TSTR; i += 256) {
        int r = i / TSTR, c = i - r * TSTR;
        int gr = bh + r, gc = bw + c;
        tile[i] = (gr < IMG && gc < IMG) ? fp[gr * IMG + gc] : 0.0f;
    }
    __syncthreads();

    const int wave = tid >> 6, lane = tid & 63;
    const int half = lane >> 5, l = lane & 31;
    const int lr = l & 15, lh = l >> 4;          // col-slot / row-parity
    const int pb  = wave * 2 + half;             // pixel 0..7 within block
    const int pxl = pb & 3, pyl = pb >> 2;
    const int oy = bh + pyl, ox = bw + pxl;
    const bool valid = (oy < NOUT) && (ox < NOUT);

    float acc0 = 0.0f, acc1 = 0.0f;
    if (valid) {
        const int iy = oy + PADV, ix = ox + PADV;
        const int theta = tmap[iy * IMG + ix];           // uniform per half-wave
        const float f0 = 0.025f + 0.0015f * (float)fmap[iy * IMG + ix];
        const float4* __restrict__ efb = (const float4*)(tab + (size_t)theta * TABQ);

        // lane l streams taps 2*(32i+l), 2*(32i+l)+1 : contiguous per inst
        float4 tw[16];
        #pragma unroll
        for (int i = 0; i < 16; ++i) tw[i] = efb[i * 32 + l];
        #pragma unroll
        for (int i = 0; i < 16; ++i)
            asm volatile("" : "+v"(tw[i].x), "+v"(tw[i].y),
                              "+v"(tw[i].z), "+v"(tw[i].w));

        const float* tbase = &tile[pyl * TSTR + pxl + 2 * lr + lh * TSTR];
        #pragma unroll
        for (int i = 0; i < 16; ++i) {
            const float* tr = tbase + 2 * i * TSTR;      // row 2i + lh
            float i0 = tr[0], i1 = tr[1];                // ds_read_b64
            float w0 = tw[i].x * __builtin_amdgcn_cosf(f0 * tw[i].y);
            float w1 = tw[i].z * __builtin_amdgcn_cosf(f0 * tw[i].w);
            acc0 = fmaf(i0, w0, acc0);
            acc1 = fmaf(i1, w1, acc1);
        }
    }

    // reduce the 32 lanes of each half-wave
    float v = acc0 + acc1;
    v += __shfl_xor(v, 1, 64);
    v += __shfl_xor(v, 2, 64);
    v += __shfl_xor(v, 4, 64);
    v += __shfl_xor(v, 8, 64);
    v += __shfl_xor(v, 16, 64);

    if (valid && l == 0)
        out[(oy + PADV) * IMG + (ox + PADV)] = v;
}

__global__ __launch_bounds__(256) void border_copy(
    const float* __restrict__ fp, float* __restrict__ out)
{
    int p = blockIdx.x * 256 + threadIdx.x;
    if (p >= IMG * IMG) return;
    int i = p / IMG, j = p - i * IMG;
    bool inner = (i >= PADV) && (i < PADV + NOUT) && (j >= PADV) && (j < PADV + NOUT);
    if (!inner) out[p] = fp[p];
}

// ---- stage 1: grid-stride min/max over out -> per-block partials ----
__global__ __launch_bounds__(256) void reduce_partials(
    const float* __restrict__ out, float2* __restrict__ part)
{
    __shared__ float smin[4], smax[4];
    float vmin = INFINITY, vmax = -INFINITY;
    for (int p = blockIdx.x * 256 + threadIdx.x; p < IMG * IMG; p += RBLK * 256) {
        float v = out[p];
        vmin = fminf(vmin, v);
        vmax = fmaxf(vmax, v);
    }
    for (int off = 32; off; off >>= 1) {
        vmin = fminf(vmin, __shfl_down(vmin, off, 64));
        vmax = fmaxf(vmax, __shfl_down(vmax, off, 64));
    }
    const int wave = threadIdx.x >> 6;
    if ((threadIdx.x & 63) == 0) { smin[wave] = vmin; smax[wave] = vmax; }
    __syncthreads();
    if (threadIdx.x == 0) {
        vmin = fminf(fminf(smin[0], smin[1]), fminf(smin[2], smin[3]));
        vmax = fmaxf(fmaxf(smax[0], smax[1]), fmaxf(smax[2], smax[3]));
        part[blockIdx.x] = make_float2(vmin, vmax);
    }
}

// ---- stage 2: single block reduces RBLK partials -> mm (plain floats) ----
__global__ __launch_bounds__(RBLK) void reduce_final(
    const float2* __restrict__ part, float* __restrict__ mm)
{
    __shared__ float smin[2], smax[2];
    float2 v = part[threadIdx.x];
    float vmin = v.x, vmax = v.y;
    for (int off = 32; off; off >>= 1) {
        vmin = fminf(vmin, __shfl_down(vmin, off, 64));
        vmax = fmaxf(vmax, __shfl_down(vmax, off, 64));
    }
    const int wave = threadIdx.x >> 6;
    if ((threadIdx.x & 63) == 0) { smin[wave] = vmin; smax[wave] = vmax; }
    __syncthreads();
    if (threadIdx.x == 0) {
        mm[0] = fminf(smin[0], smin[1]);
        mm[1] = fmaxf(smax[0], smax[1]);
    }
}

__global__ __launch_bounds__(256) void finalize(
    float* __restrict__ out, const float* __restrict__ mm)
{
    int p = blockIdx.x * 256 + threadIdx.x;
    if (p >= IMG * IMG) return;
    float mn = mm[0];
    float mx = mm[1] - mn;               // max(out - min) == max0 - min0
    float v  = out[p] - mn;
    if (mx != 0.0f) v = v / mx * 100.0f;
    out[p] = (v > 55.0f) ? 100.0f : 0.0f;
}

extern "C" void kernel_launch(void* const* d_in, const int* in_sizes, int n_in,
                              void* d_out, int out_size, void* d_ws, size_t ws_size,
                              hipStream_t stream) {
    const float* fp   = (const float*)d_in[0];
    const int*   fmap = (const int*)d_in[1];
    const int*   tmap = (const int*)d_in[2];
    float* out = (float*)d_out;

    float*  mm   = (float*)d_ws;                          // 2 floats
    float2* part = (float2*)((char*)d_ws + 256);          // RBLK float2
    float2* tab  = (float2*)((char*)d_ws + 4096);         // 180*1024*8 = 1.47 MB

    hipLaunchKernelGGL(build_eftab, dim3(NTH), dim3(256), 0, stream, tab);

    dim3 g((NOUT + PBX - 1) / PBX, (NOUT + PBY - 1) / PBY);   // 73 x 145
    hipLaunchKernelGGL(gabor_conv, g, dim3(256), 0, stream, fp, fmap, tmap, tab, out);

    int nblk = (IMG * IMG + 255) / 256;
    hipLaunchKernelGGL(border_copy,     dim3(nblk), dim3(256), 0, stream, fp, out);
    hipLaunchKernelGGL(reduce_partials, dim3(RBLK), dim3(256), 0, stream, out, part);
    hipLaunchKernelGGL(reduce_final,    dim3(1),    dim3(RBLK), 0, stream, part, mm);
    hipLaunchKernelGGL(finalize,        dim3(nblk), dim3(256), 0, stream, out, mm);
}

// Round 11
// 46.515 us; speedup vs baseline: 2.3253x; 1.0890x over previous
//
#include <hip/hip_runtime.h>
#include <math.h>

#define KS    31
#define KSP   32           // padded taps per row (col/row 31: env=0)
#define PADV  15
#define IMG   320
#define NOUT  289          // valid centered outputs (i in [15, 304))
#define NTH   180
#define TABQ  (KSP * KSP)  // 1024 float2 per theta
#define RBLK  128          // reduction blocks

// conv block geometry: 8 pixels (4 wide x 2 high), one pixel per 32-lane half
#define PBX   4
#define PBY   2
#define TROWS (PBY + KSP - 1)   // 33
#define TSTR  37                // odd LDS row stride

#define FENCE4(A,B,C,D) asm volatile("" : \
    "+v"(A.x),"+v"(A.y),"+v"(A.z),"+v"(A.w), \
    "+v"(B.x),"+v"(B.y),"+v"(B.z),"+v"(B.w), \
    "+v"(C.x),"+v"(C.y),"+v"(C.z),"+v"(C.w), \
    "+v"(D.x),"+v"(D.y),"+v"(D.z),"+v"(D.w))

// ---- per-theta (env, phi) table: w(t,f,tap) = env * cos_rev(f0 * phi) ----
// 720 blocks = 180 thetas x 4 quarters; one element per thread.
__global__ __launch_bounds__(256) void build_eftab(float2* __restrict__ tab) {
    const int t = blockIdx.x >> 2;
    const int e = (blockIdx.x & 3) * 256 + threadIdx.x;
    const float th = ((float)t / 180.0f) * 3.14159265358979323846f;
    float st, ct;
    sincosf(th, &st, &ct);
    int dy = e >> 5, dx = e & 31;
    float2 v = make_float2(0.0f, 0.0f);
    if (dy < KS && dx < KS) {
        float y = (float)(dy - PADV);
        float x = (float)(dx - PADV);
        float x_t = fmaf(x,  ct, y * st);
        float y_t = fmaf(-x, st, y * ct);
        float gamma = fmaf(0.04f, fabsf(y_t), 1.0f);      // 1 + 0.6|y_t|/15
        float gyt = gamma * y_t;
        float env = expf(-fmaf(x_t, x_t, gyt * gyt) * (1.0f / 72.0f));
        float phi = fmaf(x_t * y_t, (1.0f / 45.0f), x_t); // f_local*x_t = f0*phi
        v = make_float2(env, phi);
    }
    tab[(size_t)t * TABQ + e] = v;
}

// 256 threads = 4 waves = 8 pixels; each 32-lane half owns one pixel and
// streams its 8 KB (env,phi) slab with pipelined contiguous float4 loads.
__global__ __launch_bounds__(256) void gabor_conv(
    const float* __restrict__ fp, const int* __restrict__ fmap,
    const int* __restrict__ tmap, const float2* __restrict__ tab,
    float* __restrict__ out)
{
    __shared__ float tile[TROWS * TSTR];
    const int bh = blockIdx.y * PBY;
    const int bw = blockIdx.x * PBX;
    const int tid = threadIdx.x;

    for (int i = tid; i < TROWS * TSTR; i += 256) {
        int r = i / TSTR, c = i - r * TSTR;
        int gr = bh + r, gc = bw + c;
        tile[i] = (gr < IMG && gc < IMG) ? fp[gr * IMG + gc] : 0.0f;
    }
    __syncthreads();

    const int wave = tid >> 6, lane = tid & 63;
    const int half = lane >> 5, l = lane & 31;
    const int lr = l & 15, lh = l >> 4;          // col-slot / row-parity
    const int pb  = wave * 2 + half;             // pixel 0..7 within block
    const int pxl = pb & 3, pyl = pb >> 2;
    const int oy = bh + pyl, ox = bw + pxl;
    const bool valid = (oy < NOUT) && (ox < NOUT);

    float acc0 = 0.0f, acc1 = 0.0f;
    if (valid) {
        const int iy = oy + PADV, ix = ox + PADV;
        const int theta = tmap[iy * IMG + ix];
        const float f0 = 0.025f + 0.0015f * (float)fmap[iy * IMG + ix];
        const float4* __restrict__ efb = (const float4*)(tab + (size_t)theta * TABQ);
        const float* tbase = &tile[pyl * TSTR + pxl + 2 * lr + lh * TSTR];

        // lane l handles taps 2*(32i+l), +1 : row 2i+lh, cols 2lr, 2lr+1
#define COMP(W,i) { const float* tr_ = tbase + 2 * (i) * TSTR;               \
        float w0_ = W.x * __builtin_amdgcn_cosf(f0 * W.y);                   \
        float w1_ = W.z * __builtin_amdgcn_cosf(f0 * W.w);                   \
        acc0 = fmaf(tr_[0], w0_, acc0); acc1 = fmaf(tr_[1], w1_, acc1); }

        float4 a0 = efb[0*32+l], a1 = efb[1*32+l], a2 = efb[2*32+l], a3 = efb[3*32+l];
        float4 b0 = efb[4*32+l], b1 = efb[5*32+l], b2 = efb[6*32+l], b3 = efb[7*32+l];
        FENCE4(a0,a1,a2,a3);
        COMP(a0,0) COMP(a1,1) COMP(a2,2) COMP(a3,3)
        float4 c0 = efb[8*32+l], c1 = efb[9*32+l], c2 = efb[10*32+l], c3 = efb[11*32+l];
        FENCE4(b0,b1,b2,b3);
        COMP(b0,4) COMP(b1,5) COMP(b2,6) COMP(b3,7)
        float4 d0 = efb[12*32+l], d1 = efb[13*32+l], d2 = efb[14*32+l], d3 = efb[15*32+l];
        FENCE4(c0,c1,c2,c3);
        COMP(c0,8) COMP(c1,9) COMP(c2,10) COMP(c3,11)
        FENCE4(d0,d1,d2,d3);
        COMP(d0,12) COMP(d1,13) COMP(d2,14) COMP(d3,15)
#undef COMP
    }

    // reduce the 32 lanes of each half-wave
    float v = acc0 + acc1;
    v += __shfl_xor(v, 1, 64);
    v += __shfl_xor(v, 2, 64);
    v += __shfl_xor(v, 4, 64);
    v += __shfl_xor(v, 8, 64);
    v += __shfl_xor(v, 16, 64);

    if (valid && l == 0)
        out[(oy + PADV) * IMG + (ox + PADV)] = v;
}

// ---- stage 1: min/max over full image (inner from out, border from fp) ----
__global__ __launch_bounds__(256) void reduce_partials(
    const float* __restrict__ fp, const float* __restrict__ out,
    float2* __restrict__ part)
{
    __shared__ float smin[4], smax[4];
    float vmin = INFINITY, vmax = -INFINITY;
    for (int p = blockIdx.x * 256 + threadIdx.x; p < IMG * IMG; p += RBLK * 256) {
        int i = p / IMG, j = p - i * IMG;
        bool inner = (i >= PADV) && (i < PADV + NOUT) && (j >= PADV) && (j < PADV + NOUT);
        float v = inner ? out[p] : fp[p];
        vmin = fminf(vmin, v);
        vmax = fmaxf(vmax, v);
    }
    for (int off = 32; off; off >>= 1) {
        vmin = fminf(vmin, __shfl_down(vmin, off, 64));
        vmax = fmaxf(vmax, __shfl_down(vmax, off, 64));
    }
    const int wave = threadIdx.x >> 6;
    if ((threadIdx.x & 63) == 0) { smin[wave] = vmin; smax[wave] = vmax; }
    __syncthreads();
    if (threadIdx.x == 0) {
        vmin = fminf(fminf(smin[0], smin[1]), fminf(smin[2], smin[3]));
        vmax = fmaxf(fmaxf(smax[0], smax[1]), fmaxf(smax[2], smax[3]));
        part[blockIdx.x] = make_float2(vmin, vmax);
    }
}

// ---- stage 2: single block reduces RBLK partials -> mm (plain floats) ----
__global__ __launch_bounds__(RBLK) void reduce_final(
    const float2* __restrict__ part, float* __restrict__ mm)
{
    __shared__ float smin[2], smax[2];
    float2 v = part[threadIdx.x];
    float vmin = v.x, vmax = v.y;
    for (int off = 32; off; off >>= 1) {
        vmin = fminf(vmin, __shfl_down(vmin, off, 64));
        vmax = fmaxf(vmax, __shfl_down(vmax, off, 64));
    }
    const int wave = threadIdx.x >> 6;
    if ((threadIdx.x & 63) == 0) { smin[wave] = vmin; smax[wave] = vmax; }
    __syncthreads();
    if (threadIdx.x == 0) {
        mm[0] = fminf(smin[0], smin[1]);
        mm[1] = fmaxf(smax[0], smax[1]);
    }
}

// ---- finalize: normalize + threshold (border read from fp directly) ----
__global__ __launch_bounds__(256) void finalize(
    const float* __restrict__ fp, float* __restrict__ out,
    const float* __restrict__ mm)
{
    int p = blockIdx.x * 256 + threadIdx.x;
    if (p >= IMG * IMG) return;
    int i = p / IMG, j = p - i * IMG;
    bool inner = (i >= PADV) && (i < PADV + NOUT) && (j >= PADV) && (j < PADV + NOUT);
    float raw = inner ? out[p] : fp[p];
    float mn = mm[0];
    float mx = mm[1] - mn;               // max(out - min) == max0 - min0
    float v  = raw - mn;
    if (mx != 0.0f) v = v / mx * 100.0f;
    out[p] = (v > 55.0f) ? 100.0f : 0.0f;
}

extern "C" void kernel_launch(void* const* d_in, const int* in_sizes, int n_in,
                              void* d_out, int out_size, void* d_ws, size_t ws_size,
                              hipStream_t stream) {
    const float* fp   = (const float*)d_in[0];
    const int*   fmap = (const int*)d_in[1];
    const int*   tmap = (const int*)d_in[2];
    float* out = (float*)d_out;

    float*  mm   = (float*)d_ws;                          // 2 floats
    float2* part = (float2*)((char*)d_ws + 256);          // RBLK float2
    float2* tab  = (float2*)((char*)d_ws + 4096);         // 180*1024*8 = 1.47 MB

    hipLaunchKernelGGL(build_eftab, dim3(NTH * 4), dim3(256), 0, stream, tab);

    dim3 g((NOUT + PBX - 1) / PBX, (NOUT + PBY - 1) / PBY);   // 73 x 145
    hipLaunchKernelGGL(gabor_conv, g, dim3(256), 0, stream, fp, fmap, tmap, tab, out);

    int nblk = (IMG * IMG + 255) / 256;
    hipLaunchKernelGGL(reduce_partials, dim3(RBLK), dim3(256), 0, stream, fp, out, part);
    hipLaunchKernelGGL(reduce_final,    dim3(1),    dim3(RBLK), 0, stream, part, mm);
    hipLaunchKernelGGL(finalize,        dim3(nblk), dim3(256), 0, stream, fp, out, mm);
}

// Round 14
// 44.955 us; speedup vs baseline: 2.4060x; 1.0347x over previous
//
#include <hip/hip_runtime.h>
#include <math.h>

#define KS    31
#define KSP   32           // padded taps per row (col/row 31: env=0)
#define PADV  15
#define IMG   320
#define NOUT  289          // valid centered outputs (i in [15, 304))
#define NTH   180
#define TABQ  (KSP * KSP)  // 1024 float2 per theta (8 KB slab)
#define RBLK  128          // reduction blocks

// conv block geometry: 8 pixels (4 wide x 2 high), one pixel per 32-lane half
#define PBX   4
#define PBY   2
#define TROWS (PBY + KSP - 1)   // 33
#define TSTR  37                // odd LDS row stride (conflict-free, measured r10)
#define NSTG  (TROWS * TSTR)    // 1221

typedef float f32x4 __attribute__((ext_vector_type(4)));

// ---- per-theta (env, phi) table: w(t,f,tap) = env * cos_rev(f0 * phi) ----
__global__ __launch_bounds__(256) void build_eftab(float2* __restrict__ tab) {
    const int t = blockIdx.x >> 2;
    const int e = (blockIdx.x & 3) * 256 + threadIdx.x;
    const float th = ((float)t / 180.0f) * 3.14159265358979323846f;
    float st, ct;
    sincosf(th, &st, &ct);
    int dy = e >> 5, dx = e & 31;
    float2 v = make_float2(0.0f, 0.0f);
    if (dy < KS && dx < KS) {
        float y = (float)(dy - PADV);
        float x = (float)(dx - PADV);
        float x_t = fmaf(x,  ct, y * st);
        float y_t = fmaf(-x, st, y * ct);
        float gamma = fmaf(0.04f, fabsf(y_t), 1.0f);      // 1 + 0.6|y_t|/15
        float gyt = gamma * y_t;
        float env = expf(-fmaf(x_t, x_t, gyt * gyt) * (1.0f / 72.0f));
        float phi = fmaf(x_t * y_t, (1.0f / 45.0f), x_t); // f_local*x_t = f0*phi
        v = make_float2(env, phi);
    }
    tab[(size_t)t * TABQ + e] = v;
}

// 256 threads = 4 waves = 8 pixels; each 32-lane half owns one pixel and
// streams its 8 KB slab via counted-vmcnt pipelined dwordx4 loads.
// The waitcnt asm TIES the group's registers ("+v") so all consumers read
// post-wait SSA values — no allocator copy can observe a not-yet-landed reg.
__global__ __launch_bounds__(256, 2) void gabor_conv(
    const float* __restrict__ fp, const int* __restrict__ fmap,
    const int* __restrict__ tmap, const float2* __restrict__ tab,
    float* __restrict__ out)
{
    __shared__ float tile[NSTG];
    const int bh = blockIdx.y * PBY;
    const int bw = blockIdx.x * PBX;
    const int tid = threadIdx.x;

    for (int i = tid; i < NSTG; i += 256) {
        int r = i / TSTR, c = i - r * TSTR;
        int gr = bh + r, gc = bw + c;
        tile[i] = (gr < IMG && gc < IMG) ? fp[gr * IMG + gc] : 0.0f;
    }
    __syncthreads();

    const int wave = tid >> 6, lane = tid & 63;
    const int half = lane >> 5, l = lane & 31;
    const int lr = l & 15, lh = l >> 4;          // col-slot / row-parity
    const int pb  = wave * 2 + half;             // pixel 0..7 within block
    const int pxl = pb & 3, pyl = pb >> 2;
    const int oy = bh + pyl, ox = bw + pxl;
    const bool valid = (oy < NOUT) && (ox < NOUT);

    float acc0 = 0.0f, acc1 = 0.0f;
    if (valid) {
        const int iy = oy + PADV, ix = ox + PADV;
        const int theta = tmap[iy * IMG + ix];
        float f0 = 0.025f + 0.0015f * (float)fmap[iy * IMG + ix];
        asm volatile("" : "+v"(f0));             // force fmap load before pipeline

        // lane l, float4 index k = 32*i + l -> byte 512*i + 16*l
        unsigned long long a  =
            (unsigned long long)(tab + (size_t)theta * TABQ) + (size_t)l * 16;
        unsigned long long a2 = a + 4096;
        const float* tbase = &tile[(pyl + lh) * TSTR + pxl + 2 * lr];

        f32x4 g0a, g0b, g0c, g0d, g1a, g1b, g1c, g1d;
        f32x4 g2a, g2b, g2c, g2d, g3a, g3b, g3c, g3d;

#define ISSUE(R0,R1,R2,R3,A,O0,O1,O2,O3) asm volatile(                        \
        "global_load_dwordx4 %0, %4, off offset:" #O0 "\n\t"                  \
        "global_load_dwordx4 %1, %4, off offset:" #O1 "\n\t"                  \
        "global_load_dwordx4 %2, %4, off offset:" #O2 "\n\t"                  \
        "global_load_dwordx4 %3, %4, off offset:" #O3                         \
        : "=&v"(R0), "=&v"(R1), "=&v"(R2), "=&v"(R3) : "v"(A) : "memory")
#define WAITTIE(N,R0,R1,R2,R3)                                                \
        asm volatile("s_waitcnt vmcnt(" #N ")"                                \
            : "+v"(R0), "+v"(R1), "+v"(R2), "+v"(R3) :: "memory");            \
        __builtin_amdgcn_sched_barrier(0)
#define COMP(W, i) { const float* tr_ = tbase + 2 * (i) * TSTR;               \
        float w0_ = W.x * __builtin_amdgcn_cosf(f0 * W.y);                    \
        float w1_ = W.z * __builtin_amdgcn_cosf(f0 * W.w);                    \
        acc0 = fmaf(tr_[0], w0_, acc0); acc1 = fmaf(tr_[1], w1_, acc1); }

        ISSUE(g0a,g0b,g0c,g0d, a,  0,    512,  1024, 1536);
        ISSUE(g1a,g1b,g1c,g1d, a,  2048, 2560, 3072, 3584);
        WAITTIE(4, g0a,g0b,g0c,g0d);                 // G0 ready (G1 in flight)
        ISSUE(g2a,g2b,g2c,g2d, a2, 0,    512,  1024, 1536);
        COMP(g0a, 0) COMP(g0b, 1) COMP(g0c, 2) COMP(g0d, 3)
        __builtin_amdgcn_sched_barrier(0);
        WAITTIE(4, g1a,g1b,g1c,g1d);                 // G1 ready (G2 in flight)
        ISSUE(g3a,g3b,g3c,g3d, a2, 2048, 2560, 3072, 3584);
        COMP(g1a, 4) COMP(g1b, 5) COMP(g1c, 6) COMP(g1d, 7)
        __builtin_amdgcn_sched_barrier(0);
        WAITTIE(4, g2a,g2b,g2c,g2d);                 // G2 ready (G3 in flight)
        COMP(g2a, 8) COMP(g2b, 9) COMP(g2c, 10) COMP(g2d, 11)
        __builtin_amdgcn_sched_barrier(0);
        WAITTIE(0, g3a,g3b,g3c,g3d);                 // G3 ready
        COMP(g3a, 12) COMP(g3b, 13) COMP(g3c, 14) COMP(g3d, 15)
#undef COMP
#undef WAITTIE
#undef ISSUE
    }

    // reduce the 32 lanes of each half-wave
    float v = acc0 + acc1;
    v += __shfl_xor(v, 1, 64);
    v += __shfl_xor(v, 2, 64);
    v += __shfl_xor(v, 4, 64);
    v += __shfl_xor(v, 8, 64);
    v += __shfl_xor(v, 16, 64);

    if (valid && l == 0)
        out[(oy + PADV) * IMG + (ox + PADV)] = v;
}

// ---- stage 1: min/max over full image (inner from out, border from fp) ----
__global__ __launch_bounds__(256) void reduce_partials(
    const float* __restrict__ fp, const float* __restrict__ out,
    float2* __restrict__ part)
{
    __shared__ float smin[4], smax[4];
    float vmin = INFINITY, vmax = -INFINITY;
    for (int p = blockIdx.x * 256 + threadIdx.x; p < IMG * IMG; p += RBLK * 256) {
        int i = p / IMG, j = p - i * IMG;
        bool inner = (i >= PADV) && (i < PADV + NOUT) && (j >= PADV) && (j < PADV + NOUT);
        float v = inner ? out[p] : fp[p];
        vmin = fminf(vmin, v);
        vmax = fmaxf(vmax, v);
    }
    for (int off = 32; off; off >>= 1) {
        vmin = fminf(vmin, __shfl_down(vmin, off, 64));
        vmax = fmaxf(vmax, __shfl_down(vmax, off, 64));
    }
    const int wave = threadIdx.x >> 6;
    if ((threadIdx.x & 63) == 0) { smin[wave] = vmin; smax[wave] = vmax; }
    __syncthreads();
    if (threadIdx.x == 0) {
        vmin = fminf(fminf(smin[0], smin[1]), fminf(smin[2], smin[3]));
        vmax = fmaxf(fmaxf(smax[0], smax[1]), fmaxf(smax[2], smax[3]));
        part[blockIdx.x] = make_float2(vmin, vmax);
    }
}

// ---- stage 2: single block reduces RBLK partials -> mm (plain floats) ----
__global__ __launch_bounds__(RBLK) void reduce_final(
    const float2* __restrict__ part, float* __restrict__ mm)
{
    __shared__ float smin[2], smax[2];
    float2 v = part[threadIdx.x];
    float vmin = v.x, vmax = v.y;
    for (int off = 32; off; off >>= 1) {
        vmin = fminf(vmin, __shfl_down(vmin, off, 64));
        vmax = fmaxf(vmax, __shfl_down(vmax, off, 64));
    }
    const int wave = threadIdx.x >> 6;
    if ((threadIdx.x & 63) == 0) { smin[wave] = vmin; smax[wave] = vmax; }
    __syncthreads();
    if (threadIdx.x == 0) {
        mm[0] = fminf(smin[0], smin[1]);
        mm[1] = fmaxf(smax[0], smax[1]);
    }
}

// ---- finalize: normalize + threshold (border read from fp directly) ----
__global__ __launch_bounds__(256) void finalize(
    const float* __restrict__ fp, float* __restrict__ out,
    const float* __restrict__ mm)
{
    int p = blockIdx.x * 256 + threadIdx.x;
    if (p >= IMG * IMG) return;
    int i = p / IMG, j = p - i * IMG;
    bool inner = (i >= PADV) && (i < PADV + NOUT) && (j >= PADV) && (j < PADV + NOUT);
    float raw = inner ? out[p] : fp[p];
    float mn = mm[0];
    float mx = mm[1] - mn;               // max(out - min) == max0 - min0
    float v  = raw - mn;
    if (mx != 0.0f) v = v / mx * 100.0f;
    out[p] = (v > 55.0f) ? 100.0f : 0.0f;
}

extern "C" void kernel_launch(void* const* d_in, const int* in_sizes, int n_in,
                              void* d_out, int out_size, void* d_ws, size_t ws_size,
                              hipStream_t stream) {
    const float* fp   = (const float*)d_in[0];
    const int*   fmap = (const int*)d_in[1];
    const int*   tmap = (const int*)d_in[2];
    float* out = (float*)d_out;

    float*  mm   = (float*)d_ws;                          // 2 floats
    float2* part = (float2*)((char*)d_ws + 256);          // RBLK float2
    float2* tab  = (float2*)((char*)d_ws + 4096);         // 180*1024*8 = 1.47 MB

    hipLaunchKernelGGL(build_eftab, dim3(NTH * 4), dim3(256), 0, stream, tab);

    dim3 g((NOUT + PBX - 1) / PBX, (NOUT + PBY - 1) / PBY);   // 73 x 145
    hipLaunchKernelGGL(gabor_conv, g, dim3(256), 0, stream, fp, fmap, tmap, tab, out);

    int nblk = (IMG * IMG + 255) / 256;
    hipLaunchKernelGGL(reduce_partials, dim3(RBLK), dim3(256), 0, stream, fp, out, part);
    hipLaunchKernelGGL(reduce_final,    dim3(1),    dim3(RBLK), 0, stream, part, mm);
    hipLaunchKernelGGL(finalize,        dim3(nblk), dim3(256), 0, stream, fp, out, mm);
}